// Round 6
// baseline (304.300 us; speedup 1.0000x reference)
//
#include <hip/hip_runtime.h>
#include <math.h>

#define NNODES 100000
#define NGRAPHS 64
#define NB 391       // ceil(100000 / 256) buckets of 256 nodes
#define CAP 4608     // fixed bucket capacity (mean 4096, +8 sigma margin)
#define NBLKA 1024   // gather3A grid (4 blocks/CU)
#define NBLKB 512    // gather3B grid

// ---------- bf16 helpers (RNE pack, shift unpack) ----------

__device__ __forceinline__ unsigned int f2bf(float x) {
    union { float f; unsigned int u; } v;
    v.f = x;
    unsigned int r = v.u + 0x7FFFu + ((v.u >> 16) & 1u);
    return r >> 16;
}
__device__ __forceinline__ unsigned int pack2bf(float lo, float hi) {
    return f2bf(lo) | (f2bf(hi) << 16);
}
__device__ __forceinline__ float bflo(unsigned int u) {
    union { unsigned int u; float f; } v;
    v.u = u << 16;
    return v.f;
}
__device__ __forceinline__ float bfhi(unsigned int u) {
    union { unsigned int u; float f; } v;
    v.u = u & 0xFFFF0000u;
    return v.f;
}

#define ACC8(A, ofs, V) \
    A[(ofs) + 0] += bflo((V).x); A[(ofs) + 1] += bfhi((V).x); \
    A[(ofs) + 2] += bflo((V).y); A[(ofs) + 3] += bfhi((V).y); \
    A[(ofs) + 4] += bflo((V).z); A[(ofs) + 5] += bfhi((V).z); \
    A[(ofs) + 6] += bflo((V).w); A[(ofs) + 7] += bfhi((V).w);

// ---------- non-temporal load helpers (keep streams out of per-XCD L2) ----------

__device__ __forceinline__ int ntld(const int* p) { return __builtin_nontemporal_load(p); }
__device__ __forceinline__ int2 ntld2(const int2* p) {
    long long v = __builtin_nontemporal_load((const long long*)p);
    int2 r;
    r.x = (int)(unsigned int)(v & 0xffffffffLL);
    r.y = (int)(v >> 32);
    return r;
}

// ================= bucketed CSR build (2 kernels, fixed-capacity buckets) =================
// bucket = dst >> 8; packed edge = (dst & 255) << 17 | src  (src < 2^17)

__global__ void bucket_scatter(const int* __restrict__ src, const int* __restrict__ dst,
                               int* __restrict__ bCur, unsigned int* __restrict__ packed,
                               int E) {
    __shared__ int h[NB];
    __shared__ int cur[NB];
    for (int k = threadIdx.x; k < NB; k += 256) h[k] = 0;
    __syncthreads();
    int base = blockIdx.x * 2048 + threadIdx.x;
    int d[8], s[8], b[8];
#pragma unroll
    for (int k = 0; k < 8; ++k) {
        int e = base + k * 256;
        if (e < E) {
            d[k] = dst[e];
            s[k] = src[e];
            b[k] = d[k] >> 8;
            atomicAdd(&h[b[k]], 1);
        }
    }
    __syncthreads();
    for (int k = threadIdx.x; k < NB; k += 256) {
        int c = h[k];
        cur[k] = c ? atomicAdd(&bCur[k], c) : 0;
    }
    __syncthreads();
#pragma unroll
    for (int k = 0; k < 8; ++k) {
        int e = base + k * 256;
        if (e < E) {
            int pos = atomicAdd(&cur[b[k]], 1);
            if (pos < CAP)
                packed[(size_t)b[k] * CAP + pos] = ((unsigned int)(d[k] & 255) << 17) | (unsigned int)s[k];
        }
    }
}

// one block per bucket: histogram -> rowBE + dinv + dg + pos4 (= pos*dinv, dinv) + sorted col
__global__ void bucket_build(const unsigned int* __restrict__ packed, const int* __restrict__ bCur,
                             const int* __restrict__ batch, const float* __restrict__ pos,
                             int2* __restrict__ rowBE, int* __restrict__ col,
                             float* __restrict__ dinv, int2* __restrict__ dg,
                             float4* __restrict__ pos4, int N_) {
    __shared__ int cnt[256];
    __shared__ int bas[256];
    int tid = threadIdx.x;
    int b = blockIdx.x;
    int count = bCur[b];
    if (count > CAP) count = CAP;
    int beg = b * CAP;
    cnt[tid] = 0;
    __syncthreads();
    for (int k = beg + tid; k < beg + count; k += 256) atomicAdd(&cnt[packed[k] >> 17], 1);
    __syncthreads();
    int myCnt = cnt[tid];
    bas[tid] = myCnt;
    __syncthreads();
    for (int off = 1; off < 256; off <<= 1) {
        int v = (tid >= off) ? bas[tid - off] : 0;
        __syncthreads();
        bas[tid] += v;
        __syncthreads();
    }
    int excl = beg + ((tid > 0) ? bas[tid - 1] : 0);
    int node = (b << 8) + tid;
    if (node < N_) {
        rowBE[node] = make_int2(excl, excl + myCnt);
        float di = rsqrtf((float)myCnt + 1.0f);
        dinv[node] = di;
        dg[node] = make_int2(__float_as_int(di), batch[node]);
        pos4[node] = make_float4(pos[node * 3] * di, pos[node * 3 + 1] * di,
                                 pos[node * 3 + 2] * di, di);
    }
    __syncthreads();
    bas[tid] = excl;
    __syncthreads();
    for (int k = beg + tid; k < beg + count; k += 256) {
        unsigned int p = packed[k];
        int pos_ = atomicAdd(&bas[p >> 17], 1);
        col[pos_] = (int)(p & 0x1FFFFu);
    }
}

// ---------------- fused pos-gather + layer1-mm + layer2-mm -> bf16 z2' (group-major) ---------
// z2' output layout: [4 groups][N][32B] — group g holds channels [g*16, g*16+16).

__global__ void mm12_gp(const float4* __restrict__ pos4, const int2* __restrict__ rowBE,
                        const int* __restrict__ col, const float* __restrict__ dinv,
                        const float* __restrict__ W1, const float* __restrict__ b1,
                        const float* __restrict__ W2, uint2* __restrict__ outz, int n) {
    __shared__ float4 part[256];
    __shared__ float4 ag[64];   // .xyz = pre-di aggregate, .w = di
    __shared__ float xs[64][65];
    __shared__ float4 ws[64 * 16];
    const int tid = threadIdx.x;
    const int rowBase = blockIdx.x * 64;
    const int r = tid >> 2, t4 = tid & 3;
    const int i = rowBase + r;

    float sx = 0, sy = 0, sz = 0, dival = 0;
    if (i < n) {
        int2 be = rowBE[i];
        float4 ps = pos4[i];
        dival = ps.w;
        if (t4 == 0) { sx = ps.x; sy = ps.y; sz = ps.z; }  // self: pos*di already
        for (int j = be.x + t4; j < be.y; j += 4) {
            float4 v = pos4[ntld(&col[j])];
            sx += v.x; sy += v.y; sz += v.z;
        }
    }
    part[tid] = make_float4(sx, sy, sz, dival);
    const float4* W24 = (const float4*)W2;
    for (int idx = tid; idx < 64 * 16; idx += 256) ws[idx] = W24[idx];
    __syncthreads();
    if (tid < 64) {
        float4 p0 = part[tid * 4], p1 = part[tid * 4 + 1];
        float4 p2 = part[tid * 4 + 2], p3 = part[tid * 4 + 3];
        ag[tid] = make_float4((p0.x + p1.x) + (p2.x + p3.x),
                              (p0.y + p1.y) + (p2.y + p3.y),
                              (p0.z + p1.z) + (p2.z + p3.z), p0.w);
    }
    __syncthreads();
    for (int idx = tid; idx < 64 * 64; idx += 256) {
        int rr = idx >> 6;
        int k = idx & 63;
        float4 a = ag[rr];
        float v = b1[k] + a.w * (a.x * W1[k] + a.y * W1[64 + k] + a.z * W1[128 + k]);
        xs[rr][k] = fmaxf(v, 0.0f);
    }
    __syncthreads();

    const int f4 = tid & 15;
    const int r0 = (tid >> 4) * 4;
    float4 a0 = make_float4(0, 0, 0, 0), a1 = a0, a2 = a0, a3 = a0;
#pragma unroll 4
    for (int k = 0; k < 64; ++k) {
        float4 wv = ws[k * 16 + f4];
        float xa = xs[r0 + 0][k];
        float xb = xs[r0 + 1][k];
        float xc = xs[r0 + 2][k];
        float xd = xs[r0 + 3][k];
        a0.x += wv.x * xa; a0.y += wv.y * xa; a0.z += wv.z * xa; a0.w += wv.w * xa;
        a1.x += wv.x * xb; a1.y += wv.y * xb; a1.z += wv.z * xb; a1.w += wv.w * xb;
        a2.x += wv.x * xc; a2.y += wv.y * xc; a2.z += wv.z * xc; a2.w += wv.w * xc;
        a3.x += wv.x * xd; a3.y += wv.y * xd; a3.z += wv.z * xd; a3.w += wv.w * xd;
    }
    int i0 = rowBase + r0;
    float d0 = (i0 + 0 < n) ? dinv[i0 + 0] : 1.0f;
    float d1 = (i0 + 1 < n) ? dinv[i0 + 1] : 1.0f;
    float d2 = (i0 + 2 < n) ? dinv[i0 + 2] : 1.0f;
    float d3 = (i0 + 3 < n) ? dinv[i0 + 3] : 1.0f;
    // group-major store: f4 covers channels [f4*4, f4*4+4) -> group g = f4>>2, quad sub = f4&3
    const size_t gsel = (size_t)(f4 >> 2) * NNODES;
    const int sub = f4 & 3;
    if (i0 + 0 < n)
        outz[(gsel + (i0 + 0)) * 4 + sub] = make_uint2(pack2bf(a0.x * d0, a0.y * d0), pack2bf(a0.z * d0, a0.w * d0));
    if (i0 + 1 < n)
        outz[(gsel + (i0 + 1)) * 4 + sub] = make_uint2(pack2bf(a1.x * d1, a1.y * d1), pack2bf(a1.z * d1, a1.w * d1));
    if (i0 + 2 < n)
        outz[(gsel + (i0 + 2)) * 4 + sub] = make_uint2(pack2bf(a2.x * d2, a2.y * d2), pack2bf(a2.z * d2, a2.w * d2));
    if (i0 + 3 < n)
        outz[(gsel + (i0 + 3)) * 4 + sub] = make_uint2(pack2bf(a3.x * d3, a3.y * d3), pack2bf(a3.z * d3, a3.w * d3));
}

// ---------------- layer-2 gather, one 3.2MB channel-slice per LAUNCH (L2-resident) ----------
// Launched 4x sequentially (g = 0..3); stream ordering guarantees temporal phase separation
// (round-5 lesson: in-launch phasing fails because per-phase work < resident block capacity).
// 2 lanes per node walk the edge list in lockstep; lane t2 loads the t2-th 16B half of the
// 32B slice row -> pair coalesces to one 32B transaction/edge, and owns its 8 channels
// end-to-end (no shuffle, direct 16B store to group-major h2).

__global__ void gather2_sliced(const int2* __restrict__ rowBE, const int* __restrict__ col,
                               const uint4* __restrict__ z2s, const float* __restrict__ dinv,
                               const float* __restrict__ b2, uint4* __restrict__ h2s, int g) {
    const int tid = threadIdx.x;
    const int il = tid >> 1, t2 = tid & 1;
    const int i = blockIdx.x * 128 + il;
    if (i >= NNODES) return;
    const size_t base = (size_t)g * NNODES;

    float acc[8];
    {
        uint4 sv = z2s[(base + i) * 2 + t2];   // self term: z2'[i] = z2[i]*di (pre-scaled)
        acc[0] = bflo(sv.x); acc[1] = bfhi(sv.x);
        acc[2] = bflo(sv.y); acc[3] = bfhi(sv.y);
        acc[4] = bflo(sv.z); acc[5] = bfhi(sv.z);
        acc[6] = bflo(sv.w); acc[7] = bfhi(sv.w);
    }
    const int2 be = rowBE[i];
    int j = be.x;
    for (; j + 4 <= be.y; j += 4) {   // 4-deep batch: 4 outstanding slice loads
        int s0 = ntld(&col[j + 0]);
        int s1 = ntld(&col[j + 1]);
        int s2 = ntld(&col[j + 2]);
        int s3 = ntld(&col[j + 3]);
        uint4 v0 = z2s[(base + s0) * 2 + t2];
        uint4 v1 = z2s[(base + s1) * 2 + t2];
        uint4 v2 = z2s[(base + s2) * 2 + t2];
        uint4 v3 = z2s[(base + s3) * 2 + t2];
        ACC8(acc, 0, v0)
        ACC8(acc, 0, v1)
        ACC8(acc, 0, v2)
        ACC8(acc, 0, v3)
    }
    for (; j < be.y; ++j) {
        uint4 v = z2s[(base + (size_t)ntld(&col[j])) * 2 + t2];
        ACC8(acc, 0, v)
    }

    const float di = dinv[i];
    const float* bv = b2 + g * 16 + t2 * 8;
    float h[8];
#pragma unroll
    for (int k = 0; k < 8; ++k) h[k] = fmaxf(acc[k] * di + bv[k], 0.0f);
    h2s[(base + i) * 2 + t2] = make_uint4(pack2bf(h[0], h[1]), pack2bf(h[2], h[3]),
                                          pack2bf(h[4], h[5]), pack2bf(h[6], h[7]));
}

// ---------------- layer-3 matmul: h2 (group-major) @ W3 scaled by dinv -> yA/yB -------------
// yA[N] 32B rows = ch0-15 (3.2MB, fits per-XCD L2); yB[N] 16B rows = ch16-23 (1.6MB).

__device__ __forceinline__ void st_y(uint2* __restrict__ yA, uint2* __restrict__ yB,
                                     int i, int f4, uint2 v) {
    if (f4 < 4) yA[(size_t)i * 4 + f4] = v;
    else        yB[(size_t)i * 2 + (f4 - 4)] = v;
}

__global__ void mm3_b16(const uint4* __restrict__ xb, const float* __restrict__ W,
                        const float* __restrict__ dinv, uint2* __restrict__ yA,
                        uint2* __restrict__ yB, int n) {
    __shared__ float xs[128][65];
    __shared__ float4 ws[64 * 6];
    const int tid = threadIdx.x;
    const int rowBase = blockIdx.x * 128;

    for (int idx = tid; idx < 128 * 8; idx += 192) {
        int r = idx >> 3;
        int c8 = idx & 7;   // channel octet; group = c8>>1, half = c8&1
        int gr = rowBase + r;
        uint4 v = (gr < n) ? xb[((size_t)(c8 >> 1) * NNODES + gr) * 2 + (c8 & 1)]
                           : make_uint4(0, 0, 0, 0);
        float* xp = &xs[r][c8 * 8];
        xp[0] = bflo(v.x); xp[1] = bfhi(v.x);
        xp[2] = bflo(v.y); xp[3] = bfhi(v.y);
        xp[4] = bflo(v.z); xp[5] = bfhi(v.z);
        xp[6] = bflo(v.w); xp[7] = bfhi(v.w);
    }
    const float4* W4 = (const float4*)W;
    for (int idx = tid; idx < 64 * 6; idx += 192) ws[idx] = W4[idx];
    __syncthreads();

    const int f4 = tid % 6;
    const int r0 = (tid / 6) * 4;
    float4 a0 = make_float4(0, 0, 0, 0), a1 = a0, a2 = a0, a3 = a0;
#pragma unroll 4
    for (int k = 0; k < 64; ++k) {
        float4 wv = ws[k * 6 + f4];
        float xa = xs[r0 + 0][k];
        float xb_ = xs[r0 + 1][k];
        float xc = xs[r0 + 2][k];
        float xd = xs[r0 + 3][k];
        a0.x += wv.x * xa; a0.y += wv.y * xa; a0.z += wv.z * xa; a0.w += wv.w * xa;
        a1.x += wv.x * xb_; a1.y += wv.y * xb_; a1.z += wv.z * xb_; a1.w += wv.w * xb_;
        a2.x += wv.x * xc; a2.y += wv.y * xc; a2.z += wv.z * xc; a2.w += wv.w * xc;
        a3.x += wv.x * xd; a3.y += wv.y * xd; a3.z += wv.z * xd; a3.w += wv.w * xd;
    }
    int i0 = rowBase + r0;
    float d0 = (i0 + 0 < n) ? dinv[i0 + 0] : 1.0f;
    float d1 = (i0 + 1 < n) ? dinv[i0 + 1] : 1.0f;
    float d2 = (i0 + 2 < n) ? dinv[i0 + 2] : 1.0f;
    float d3 = (i0 + 3 < n) ? dinv[i0 + 3] : 1.0f;
    if (i0 + 0 < n)
        st_y(yA, yB, i0 + 0, f4, make_uint2(pack2bf(a0.x * d0, a0.y * d0), pack2bf(a0.z * d0, a0.w * d0)));
    if (i0 + 1 < n)
        st_y(yA, yB, i0 + 1, f4, make_uint2(pack2bf(a1.x * d1, a1.y * d1), pack2bf(a1.z * d1, a1.w * d1)));
    if (i0 + 2 < n)
        st_y(yA, yB, i0 + 2, f4, make_uint2(pack2bf(a2.x * d2, a2.y * d2), pack2bf(a2.z * d2, a2.w * d2)));
    if (i0 + 3 < n)
        st_y(yA, yB, i0 + 3, f4, make_uint2(pack2bf(a3.x * d3, a3.y * d3), pack2bf(a3.z * d3, a3.w * d3)));
}

// ---------------- gather layer3 + pool, channel-phased so the table fits per-XCD L2 ----------
// gather3A: ch0-15 from yA (3.2MB). 4 tasks/node: (half = bit0, r = bit1).
// gather3B: ch16-23 from yB (1.6MB) + node counts. 2 tasks/node (half = bit0).
// Edge halves merged in-wave via shfl_xor(1); col/rowBE/dg non-temporal.

__global__ void gather3A(const int2* __restrict__ rowBE, const int* __restrict__ col,
                         const uint4* __restrict__ yA, const int2* __restrict__ dg,
                         float* __restrict__ partA) {
    __shared__ float lpool[NGRAPHS * 16];
    for (int k = threadIdx.x; k < NGRAPHS * 16; k += 256) lpool[k] = 0.0f;
    __syncthreads();

    const int T = NNODES * 4;
    const int stride = NBLKA * 256;
    for (int t = blockIdx.x * 256 + threadIdx.x; t < T; t += stride) {
        int i = t >> 2;
        int half = t & 1;
        int r = (t >> 1) & 1;
        int2 wi = ntld2(&dg[i]);
        float di = __int_as_float(wi.x);
        int g = wi.y;
        int2 be = ntld2(&rowBE[i]);
        int mid = be.x + ((be.y - be.x + 1) >> 1);
        int a = half ? mid : be.x;
        int b = half ? be.y : mid;
        float acc[8] = {0, 0, 0, 0, 0, 0, 0, 0};
        if (!half) {
            uint4 sv = yA[(size_t)i * 2 + r];  // self term (pre-scaled)
            acc[0] = bflo(sv.x); acc[1] = bfhi(sv.x);
            acc[2] = bflo(sv.y); acc[3] = bfhi(sv.y);
            acc[4] = bflo(sv.z); acc[5] = bfhi(sv.z);
            acc[6] = bflo(sv.w); acc[7] = bfhi(sv.w);
        }
        int j = a;
        for (; j + 8 <= b; j += 8) {
            int s[8];
            uint4 v[8];
#pragma unroll
            for (int k = 0; k < 8; ++k) s[k] = ntld(&col[j + k]);
#pragma unroll
            for (int k = 0; k < 8; ++k) v[k] = yA[(size_t)s[k] * 2 + r];
#pragma unroll
            for (int k = 0; k < 8; ++k) {
                acc[0] += bflo(v[k].x); acc[1] += bfhi(v[k].x);
                acc[2] += bflo(v[k].y); acc[3] += bfhi(v[k].y);
                acc[4] += bflo(v[k].z); acc[5] += bfhi(v[k].z);
                acc[6] += bflo(v[k].w); acc[7] += bfhi(v[k].w);
            }
        }
        for (; j < b; ++j) {
            uint4 v = yA[(size_t)ntld(&col[j]) * 2 + r];
            acc[0] += bflo(v.x); acc[1] += bfhi(v.x);
            acc[2] += bflo(v.y); acc[3] += bfhi(v.y);
            acc[4] += bflo(v.z); acc[5] += bfhi(v.z);
            acc[6] += bflo(v.w); acc[7] += bfhi(v.w);
        }
        // merge the two edge-halves (lanes l and l^1 share node i and r)
#pragma unroll
        for (int k = 0; k < 8; ++k) acc[k] += __shfl_xor(acc[k], 1);
        if (!half) {
            float* lp = &lpool[g * 16 + r * 8];
#pragma unroll
            for (int k = 0; k < 8; ++k) atomicAdd(&lp[k], acc[k] * di);
        }
    }
    __syncthreads();
    float* pp = partA + (size_t)blockIdx.x * (NGRAPHS * 16);
    for (int k = threadIdx.x; k < NGRAPHS * 16; k += 256) pp[k] = lpool[k];
}

__global__ void gather3B(const int2* __restrict__ rowBE, const int* __restrict__ col,
                         const uint4* __restrict__ yB, const int2* __restrict__ dg,
                         float* __restrict__ partB, float* __restrict__ cpart) {
    __shared__ float lpool[NGRAPHS * 8];
    __shared__ float lcnt[NGRAPHS];
    for (int k = threadIdx.x; k < NGRAPHS * 8; k += 256) lpool[k] = 0.0f;
    for (int k = threadIdx.x; k < NGRAPHS; k += 256) lcnt[k] = 0.0f;
    __syncthreads();

    const int T = NNODES * 2;
    const int stride = NBLKB * 256;
    for (int t = blockIdx.x * 256 + threadIdx.x; t < T; t += stride) {
        int i = t >> 1;
        int half = t & 1;
        int2 wi = ntld2(&dg[i]);
        float di = __int_as_float(wi.x);
        int g = wi.y;
        int2 be = ntld2(&rowBE[i]);
        int mid = be.x + ((be.y - be.x + 1) >> 1);
        int a = half ? mid : be.x;
        int b = half ? be.y : mid;
        float acc[8] = {0, 0, 0, 0, 0, 0, 0, 0};
        if (!half) {
            uint4 sv = yB[i];
            acc[0] = bflo(sv.x); acc[1] = bfhi(sv.x);
            acc[2] = bflo(sv.y); acc[3] = bfhi(sv.y);
            acc[4] = bflo(sv.z); acc[5] = bfhi(sv.z);
            acc[6] = bflo(sv.w); acc[7] = bfhi(sv.w);
        }
        int j = a;
        for (; j + 8 <= b; j += 8) {
            int s[8];
            uint4 v[8];
#pragma unroll
            for (int k = 0; k < 8; ++k) s[k] = ntld(&col[j + k]);
#pragma unroll
            for (int k = 0; k < 8; ++k) v[k] = yB[s[k]];
#pragma unroll
            for (int k = 0; k < 8; ++k) {
                acc[0] += bflo(v[k].x); acc[1] += bfhi(v[k].x);
                acc[2] += bflo(v[k].y); acc[3] += bfhi(v[k].y);
                acc[4] += bflo(v[k].z); acc[5] += bfhi(v[k].z);
                acc[6] += bflo(v[k].w); acc[7] += bfhi(v[k].w);
            }
        }
        for (; j < b; ++j) {
            uint4 v = yB[ntld(&col[j])];
            acc[0] += bflo(v.x); acc[1] += bfhi(v.x);
            acc[2] += bflo(v.y); acc[3] += bfhi(v.y);
            acc[4] += bflo(v.z); acc[5] += bfhi(v.z);
            acc[6] += bflo(v.w); acc[7] += bfhi(v.w);
        }
#pragma unroll
        for (int k = 0; k < 8; ++k) acc[k] += __shfl_xor(acc[k], 1);
        if (!half) {
            float* lp = &lpool[g * 8];
#pragma unroll
            for (int k = 0; k < 8; ++k) atomicAdd(&lp[k], acc[k] * di);
            atomicAdd(&lcnt[g], 1.0f);
        }
    }
    __syncthreads();
    float* pp = partB + (size_t)blockIdx.x * (NGRAPHS * 8);
    for (int k = threadIdx.x; k < NGRAPHS * 8; k += 256) pp[k] = lpool[k];
    float* cp = cpart + (size_t)blockIdx.x * NGRAPHS;
    for (int k = threadIdx.x; k < NGRAPHS; k += 256) cp[k] = lcnt[k];
}

// one wave (64 lanes) per output element; lanes stride over the block partials
__global__ void pool_finish(const float* __restrict__ partA, const float* __restrict__ partB,
                            const float* __restrict__ cpart, const float* __restrict__ b3,
                            float* __restrict__ out) {
    int w = blockIdx.x * 4 + (threadIdx.x >> 6);
    int lane = threadIdx.x & 63;
    if (w >= NGRAPHS * 24) return;
    int g = w / 24;
    int c = w - g * 24;
    float s = 0.0f, cn = 0.0f;
    if (c < 16) {
        for (int b = lane; b < NBLKA; b += 64) s += partA[(size_t)b * (NGRAPHS * 16) + g * 16 + c];
    } else {
        for (int b = lane; b < NBLKB; b += 64) s += partB[(size_t)b * (NGRAPHS * 8) + g * 8 + (c - 16)];
    }
    for (int b = lane; b < NBLKB; b += 64) cn += cpart[(size_t)b * NGRAPHS + g];
#pragma unroll
    for (int off = 32; off > 0; off >>= 1) {
        s += __shfl_down(s, off);
        cn += __shfl_down(cn, off);
    }
    if (lane == 0) out[w] = tanhf(s / fmaxf(cn, 1.0f) + b3[c]);
}

// ---------------- launch ----------------

static inline int gridFor(long long total, int block) {
    return (int)((total + block - 1) / block);
}

extern "C" void kernel_launch(void* const* d_in, const int* in_sizes, int n_in,
                              void* d_out, int out_size, void* d_ws, size_t ws_size,
                              hipStream_t stream) {
    const float* pos   = (const float*)d_in[0];
    const int*   ei    = (const int*)d_in[1];
    const int*   batch = (const int*)d_in[2];
    const float* W1    = (const float*)d_in[3];
    const float* b1    = (const float*)d_in[4];
    const float* W2    = (const float*)d_in[5];
    const float* b2    = (const float*)d_in[6];
    const float* W3    = (const float*)d_in[7];
    const float* b3    = (const float*)d_in[8];
    float*       out   = (float*)d_out;

    const int N = NNODES;
    const int E = in_sizes[1] / 2;
    const int* src = ei;
    const int* dst = ei + E;

    // ---- workspace layout (16B-aligned chunks first) ----
    char* p = (char*)d_ws;
    uint4*  z2s    = (uint4*)p;         p += (size_t)N * 8 * sizeof(uint4);   // bf16 z2' [4][N][32B]
    uint4*  h2s    = (uint4*)p;         p += (size_t)N * 8 * sizeof(uint4);   // bf16 h2  [4][N][32B]
    uint4*  yA     = (uint4*)p;         p += (size_t)N * 2 * sizeof(uint4);   // bf16 y0' ch0-15 (3.2MB)
    uint4*  yB     = (uint4*)p;         p += (size_t)N * 1 * sizeof(uint4);   // bf16 y0' ch16-23 (1.6MB)
    float4* pos4   = (float4*)p;        p += (size_t)N * sizeof(float4);      // {pos*di, di}
    int2*   rowBE  = (int2*)p;          p += (size_t)N * sizeof(int2);
    int2*   dg     = (int2*)p;          p += (size_t)N * sizeof(int2);
    float*  dinv   = (float*)p;         p += (size_t)N * sizeof(float);
    int*    bCur   = (int*)p;           p += NB * sizeof(int);
    unsigned int* packed = (unsigned int*)p;  p += (size_t)NB * CAP * sizeof(unsigned int);
    int*    col    = (int*)p;           p += (size_t)NB * CAP * sizeof(int);
    // partials aliased onto z2s (12.8MB; dead after the last gather2_sliced launch).
    float*  partA  = (float*)z2s;
    float*  partB  = partA + (size_t)NBLKA * NGRAPHS * 16;
    float*  cpartB = partB + (size_t)NBLKB * NGRAPHS * 8;

    const int B = 256;
    const int edgeBlocks = gridFor(E, 2048);

    // ---- CSR build: 2 kernels, fixed-capacity buckets ----
    hipMemsetAsync(bCur, 0, NB * sizeof(int), stream);
    bucket_scatter<<<edgeBlocks, 256, 0, stream>>>(src, dst, bCur, packed, E);
    bucket_build<<<NB, 256, 0, stream>>>(packed, bCur, batch, pos, rowBE, col, dinv, dg, pos4, N);

    // ---- fused pos-gather + mm1 + mm2 -> z2' bf16 (group-major) ----
    mm12_gp<<<gridFor(N, 64), 256, 0, stream>>>(pos4, rowBE, col, dinv, W1, b1, W2, (uint2*)z2s, N);

    // ---- layer-2 gather: 4 sequential launches, one L2-resident 3.2MB slice each ----
    for (int g = 0; g < 4; ++g)
        gather2_sliced<<<gridFor((long long)N * 2, B), B, 0, stream>>>(rowBE, col, z2s, dinv, b2, h2s, g);

    // ---- layer-3 matmul (streamed) -> yA/yB split tables ----
    mm3_b16<<<gridFor(N, 128), 192, 0, stream>>>(h2s, W3, dinv, (uint2*)yA, (uint2*)yB, N);

    // ---- channel-phased gather+pool ----
    gather3A<<<NBLKA, 256, 0, stream>>>(rowBE, col, yA, dg, partA);
    gather3B<<<NBLKB, 256, 0, stream>>>(rowBE, col, yB, dg, partB, cpartB);
    pool_finish<<<gridFor((long long)NGRAPHS * 24 * 64, B), B, 0, stream>>>(partA, partB, cpartB, b3, out);
}

// Round 7
// 271.375 us; speedup vs baseline: 1.1213x; 1.1213x over previous
//
#include <hip/hip_runtime.h>
#include <math.h>

#define NNODES 100000
#define NGRAPHS 64
#define NB 391       // ceil(100000 / 256) buckets of 256 nodes
#define CAP 4608     // fixed bucket capacity (mean 4096, +8 sigma margin)
#define NBLKA 2048   // gather3A grid: 8 blocks/CU (VGPR 44 / LDS 4KB allow the full wave cap)
#define NBLKB 1024   // gather3B grid

// ---------- bf16 helpers (RNE pack, shift unpack) ----------

__device__ __forceinline__ unsigned int f2bf(float x) {
    union { float f; unsigned int u; } v;
    v.f = x;
    unsigned int r = v.u + 0x7FFFu + ((v.u >> 16) & 1u);
    return r >> 16;
}
__device__ __forceinline__ unsigned int pack2bf(float lo, float hi) {
    return f2bf(lo) | (f2bf(hi) << 16);
}
__device__ __forceinline__ float bflo(unsigned int u) {
    union { unsigned int u; float f; } v;
    v.u = u << 16;
    return v.f;
}
__device__ __forceinline__ float bfhi(unsigned int u) {
    union { unsigned int u; float f; } v;
    v.u = u & 0xFFFF0000u;
    return v.f;
}

// ---------- non-temporal load helpers (keep streams out of per-XCD L2) ----------

__device__ __forceinline__ int ntld(const int* p) { return __builtin_nontemporal_load(p); }
__device__ __forceinline__ int2 ntld2(const int2* p) {
    long long v = __builtin_nontemporal_load((const long long*)p);
    int2 r;
    r.x = (int)(unsigned int)(v & 0xffffffffLL);
    r.y = (int)(v >> 32);
    return r;
}

// ================= bucketed CSR build (2 kernels, fixed-capacity buckets) =================
// bucket = dst >> 8; packed edge = (dst & 255) << 17 | src  (src < 2^17)

__global__ void bucket_scatter(const int* __restrict__ src, const int* __restrict__ dst,
                               int* __restrict__ bCur, unsigned int* __restrict__ packed,
                               int E) {
    __shared__ int h[NB];
    __shared__ int cur[NB];
    for (int k = threadIdx.x; k < NB; k += 256) h[k] = 0;
    __syncthreads();
    int base = blockIdx.x * 2048 + threadIdx.x;
    int d[8], s[8], b[8];
#pragma unroll
    for (int k = 0; k < 8; ++k) {
        int e = base + k * 256;
        if (e < E) {
            d[k] = dst[e];
            s[k] = src[e];
            b[k] = d[k] >> 8;
            atomicAdd(&h[b[k]], 1);
        }
    }
    __syncthreads();
    for (int k = threadIdx.x; k < NB; k += 256) {
        int c = h[k];
        cur[k] = c ? atomicAdd(&bCur[k], c) : 0;
    }
    __syncthreads();
#pragma unroll
    for (int k = 0; k < 8; ++k) {
        int e = base + k * 256;
        if (e < E) {
            int pos = atomicAdd(&cur[b[k]], 1);
            if (pos < CAP)
                packed[(size_t)b[k] * CAP + pos] = ((unsigned int)(d[k] & 255) << 17) | (unsigned int)s[k];
        }
    }
}

// one block per bucket: histogram -> rowBE + dinv + dg + pos4 (= pos*dinv, dinv) + sorted col
__global__ void bucket_build(const unsigned int* __restrict__ packed, const int* __restrict__ bCur,
                             const int* __restrict__ batch, const float* __restrict__ pos,
                             int2* __restrict__ rowBE, int* __restrict__ col,
                             float* __restrict__ dinv, int2* __restrict__ dg,
                             float4* __restrict__ pos4, int N_) {
    __shared__ int cnt[256];
    __shared__ int bas[256];
    int tid = threadIdx.x;
    int b = blockIdx.x;
    int count = bCur[b];
    if (count > CAP) count = CAP;
    int beg = b * CAP;
    cnt[tid] = 0;
    __syncthreads();
    for (int k = beg + tid; k < beg + count; k += 256) atomicAdd(&cnt[packed[k] >> 17], 1);
    __syncthreads();
    int myCnt = cnt[tid];
    bas[tid] = myCnt;
    __syncthreads();
    for (int off = 1; off < 256; off <<= 1) {
        int v = (tid >= off) ? bas[tid - off] : 0;
        __syncthreads();
        bas[tid] += v;
        __syncthreads();
    }
    int excl = beg + ((tid > 0) ? bas[tid - 1] : 0);
    int node = (b << 8) + tid;
    if (node < N_) {
        rowBE[node] = make_int2(excl, excl + myCnt);
        float di = rsqrtf((float)myCnt + 1.0f);
        dinv[node] = di;
        dg[node] = make_int2(__float_as_int(di), batch[node]);
        pos4[node] = make_float4(pos[node * 3] * di, pos[node * 3 + 1] * di,
                                 pos[node * 3 + 2] * di, di);
    }
    __syncthreads();
    bas[tid] = excl;
    __syncthreads();
    for (int k = beg + tid; k < beg + count; k += 256) {
        unsigned int p = packed[k];
        int pos_ = atomicAdd(&bas[p >> 17], 1);
        col[pos_] = (int)(p & 0x1FFFFu);
    }
}

// ---------------- fused pos-gather + layer1-mm + layer2-mm -> bf16 z2' (= z2*dinv) ------------

__global__ void mm12_gp(const float4* __restrict__ pos4, const int2* __restrict__ rowBE,
                        const int* __restrict__ col, const float* __restrict__ dinv,
                        const float* __restrict__ W1, const float* __restrict__ b1,
                        const float* __restrict__ W2, uint2* __restrict__ outb, int n) {
    __shared__ float4 part[256];
    __shared__ float4 ag[64];   // .xyz = pre-di aggregate, .w = di
    __shared__ float xs[64][65];
    __shared__ float4 ws[64 * 16];
    const int tid = threadIdx.x;
    const int rowBase = blockIdx.x * 64;
    const int r = tid >> 2, t4 = tid & 3;
    const int i = rowBase + r;

    float sx = 0, sy = 0, sz = 0, dival = 0;
    if (i < n) {
        int2 be = rowBE[i];
        float4 ps = pos4[i];
        dival = ps.w;
        if (t4 == 0) { sx = ps.x; sy = ps.y; sz = ps.z; }  // self: pos*di already
        for (int j = be.x + t4; j < be.y; j += 4) {
            float4 v = pos4[ntld(&col[j])];
            sx += v.x; sy += v.y; sz += v.z;
        }
    }
    part[tid] = make_float4(sx, sy, sz, dival);
    const float4* W24 = (const float4*)W2;
    for (int idx = tid; idx < 64 * 16; idx += 256) ws[idx] = W24[idx];
    __syncthreads();
    if (tid < 64) {
        float4 p0 = part[tid * 4], p1 = part[tid * 4 + 1];
        float4 p2 = part[tid * 4 + 2], p3 = part[tid * 4 + 3];
        ag[tid] = make_float4((p0.x + p1.x) + (p2.x + p3.x),
                              (p0.y + p1.y) + (p2.y + p3.y),
                              (p0.z + p1.z) + (p2.z + p3.z), p0.w);
    }
    __syncthreads();
    for (int idx = tid; idx < 64 * 64; idx += 256) {
        int rr = idx >> 6;
        int k = idx & 63;
        float4 a = ag[rr];
        float v = b1[k] + a.w * (a.x * W1[k] + a.y * W1[64 + k] + a.z * W1[128 + k]);
        xs[rr][k] = fmaxf(v, 0.0f);
    }
    __syncthreads();

    const int f4 = tid & 15;
    const int r0 = (tid >> 4) * 4;
    float4 a0 = make_float4(0, 0, 0, 0), a1 = a0, a2 = a0, a3 = a0;
#pragma unroll 4
    for (int k = 0; k < 64; ++k) {
        float4 wv = ws[k * 16 + f4];
        float xa = xs[r0 + 0][k];
        float xb = xs[r0 + 1][k];
        float xc = xs[r0 + 2][k];
        float xd = xs[r0 + 3][k];
        a0.x += wv.x * xa; a0.y += wv.y * xa; a0.z += wv.z * xa; a0.w += wv.w * xa;
        a1.x += wv.x * xb; a1.y += wv.y * xb; a1.z += wv.z * xb; a1.w += wv.w * xb;
        a2.x += wv.x * xc; a2.y += wv.y * xc; a2.z += wv.z * xc; a2.w += wv.w * xc;
        a3.x += wv.x * xd; a3.y += wv.y * xd; a3.z += wv.z * xd; a3.w += wv.w * xd;
    }
    int i0 = rowBase + r0;
    float d0 = (i0 + 0 < n) ? dinv[i0 + 0] : 1.0f;
    float d1 = (i0 + 1 < n) ? dinv[i0 + 1] : 1.0f;
    float d2 = (i0 + 2 < n) ? dinv[i0 + 2] : 1.0f;
    float d3 = (i0 + 3 < n) ? dinv[i0 + 3] : 1.0f;
    if (i0 + 0 < n)
        outb[(size_t)(i0 + 0) * 16 + f4] = make_uint2(pack2bf(a0.x * d0, a0.y * d0), pack2bf(a0.z * d0, a0.w * d0));
    if (i0 + 1 < n)
        outb[(size_t)(i0 + 1) * 16 + f4] = make_uint2(pack2bf(a1.x * d1, a1.y * d1), pack2bf(a1.z * d1, a1.w * d1));
    if (i0 + 2 < n)
        outb[(size_t)(i0 + 2) * 16 + f4] = make_uint2(pack2bf(a2.x * d2, a2.y * d2), pack2bf(a2.z * d2, a2.w * d2));
    if (i0 + 3 < n)
        outb[(size_t)(i0 + 3) * 16 + f4] = make_uint2(pack2bf(a3.x * d3, a3.y * d3), pack2bf(a3.z * d3, a3.w * d3));
}

// ---------------- fused gather layer2 + layer-3 matmul -> bf16 yA/yB directly ----------------
// Per block: 256 threads = 32 nodes x 8 channel-lanes. Phase 1: each lane accumulates 8
// channels over the node's edges, h2 = relu(acc*di + b2) -> stage f32 in LDS. Phase 2:
// 192 tasks (32 nodes x 6 col-quads) compute y0' = (h2 @ W3)*di -> split tables.

__device__ __forceinline__ void st_y(uint2* __restrict__ yA, uint2* __restrict__ yB,
                                     int i, int f4, uint2 v) {
    if (f4 < 4) yA[(size_t)i * 4 + f4] = v;
    else        yB[(size_t)i * 2 + (f4 - 4)] = v;
}

__global__ void gather2_mm3(const int2* __restrict__ rowBE, const int* __restrict__ col,
                            const uint4* __restrict__ h, const float* __restrict__ dinv,
                            const float* __restrict__ bias, const float* __restrict__ W3,
                            uint2* __restrict__ yA, uint2* __restrict__ yB) {
    __shared__ float hs[32][65];   // f32 h2 rows for this block's 32 nodes
    __shared__ float dd[32];       // dinv per local node
    __shared__ float w3s[64 * 24]; // W3 [k][c] row-major (6KB)
    const int tid = threadIdx.x;
    for (int idx = tid; idx < 64 * 24 / 4; idx += 256)
        ((float4*)w3s)[idx] = ((const float4*)W3)[idx];

    const int t = blockIdx.x * 256 + tid;   // grid is exact: N*8/256 = 3125 blocks
    const int i = t >> 3;
    const int c8 = t & 7;
    const float di = dinv[i];
    const int2 be = rowBE[i];
    float acc[8];
    {
        uint4 sv = h[t];  // z2'[i] = z2[i]*di  -> exactly the self-loop inner term
        acc[0] = bflo(sv.x); acc[1] = bfhi(sv.x);
        acc[2] = bflo(sv.y); acc[3] = bfhi(sv.y);
        acc[4] = bflo(sv.z); acc[5] = bfhi(sv.z);
        acc[6] = bflo(sv.w); acc[7] = bfhi(sv.w);
    }
    int j = be.x;
    for (; j + 8 <= be.y; j += 8) {
        int s[8];
        uint4 v[8];
#pragma unroll
        for (int k = 0; k < 8; ++k) s[k] = ntld(&col[j + k]);
#pragma unroll
        for (int k = 0; k < 8; ++k) v[k] = h[(size_t)s[k] * 8 + c8];
#pragma unroll
        for (int k = 0; k < 8; ++k) {
            acc[0] += bflo(v[k].x); acc[1] += bfhi(v[k].x);
            acc[2] += bflo(v[k].y); acc[3] += bfhi(v[k].y);
            acc[4] += bflo(v[k].z); acc[5] += bfhi(v[k].z);
            acc[6] += bflo(v[k].w); acc[7] += bfhi(v[k].w);
        }
    }
    for (; j < be.y; ++j) {
        uint4 v = h[(size_t)ntld(&col[j]) * 8 + c8];
        acc[0] += bflo(v.x); acc[1] += bfhi(v.x);
        acc[2] += bflo(v.y); acc[3] += bfhi(v.y);
        acc[4] += bflo(v.z); acc[5] += bfhi(v.z);
        acc[6] += bflo(v.w); acc[7] += bfhi(v.w);
    }
    const int il = tid >> 3;
    {
        const float* bv = bias + c8 * 8;
        float* hp = &hs[il][c8 * 8];
#pragma unroll
        for (int k = 0; k < 8; ++k) hp[k] = fmaxf(acc[k] * di + bv[k], 0.0f);
        if (c8 == 0) dd[il] = di;
    }
    __syncthreads();

    // Phase 2: 32 nodes x 6 col-quads; each task: 4 output cols, 64 MACs each
    if (tid < 192) {
        const int node = tid / 6;
        const int f4 = tid - node * 6;
        const int gi = blockIdx.x * 32 + node;
        const float dloc = dd[node];
        const float* hrow = hs[node];
        const float* wp = &w3s[f4 * 4];
        float c0 = 0, c1 = 0, c2 = 0, c3 = 0;
#pragma unroll 4
        for (int k = 0; k < 64; ++k) {
            float hv = hrow[k];
            c0 += hv * wp[k * 24 + 0];
            c1 += hv * wp[k * 24 + 1];
            c2 += hv * wp[k * 24 + 2];
            c3 += hv * wp[k * 24 + 3];
        }
        st_y(yA, yB, gi, f4, make_uint2(pack2bf(c0 * dloc, c1 * dloc),
                                        pack2bf(c2 * dloc, c3 * dloc)));
    }
}

// ---------------- gather layer3 + pool, channel-phased so the table fits per-XCD L2 ----------
// gather3A: ch0-15 from yA (3.2MB). 4 tasks/node: (half = bit0, r = bit1).
// gather3B: ch16-23 from yB (1.6MB) + node counts. 2 tasks/node (half = bit0).
// Edge halves merged in-wave via shfl_xor(1); col/rowBE/dg non-temporal.
// Grids sized for 8 blocks/CU co-residency; grid-stride degenerates to <=1 task/thread.

__global__ void gather3A(const int2* __restrict__ rowBE, const int* __restrict__ col,
                         const uint4* __restrict__ yA, const int2* __restrict__ dg,
                         float* __restrict__ partA) {
    __shared__ float lpool[NGRAPHS * 16];
    for (int k = threadIdx.x; k < NGRAPHS * 16; k += 256) lpool[k] = 0.0f;
    __syncthreads();

    const int T = NNODES * 4;
    const int stride = NBLKA * 256;
    for (int t = blockIdx.x * 256 + threadIdx.x; t < T; t += stride) {
        int i = t >> 2;
        int half = t & 1;
        int r = (t >> 1) & 1;
        int2 wi = ntld2(&dg[i]);
        float di = __int_as_float(wi.x);
        int g = wi.y;
        int2 be = ntld2(&rowBE[i]);
        int mid = be.x + ((be.y - be.x + 1) >> 1);
        int a = half ? mid : be.x;
        int b = half ? be.y : mid;
        float acc[8] = {0, 0, 0, 0, 0, 0, 0, 0};
        if (!half) {
            uint4 sv = yA[(size_t)i * 2 + r];  // self term (pre-scaled)
            acc[0] = bflo(sv.x); acc[1] = bfhi(sv.x);
            acc[2] = bflo(sv.y); acc[3] = bfhi(sv.y);
            acc[4] = bflo(sv.z); acc[5] = bfhi(sv.z);
            acc[6] = bflo(sv.w); acc[7] = bfhi(sv.w);
        }
        int j = a;
        for (; j + 8 <= b; j += 8) {
            int s[8];
            uint4 v[8];
#pragma unroll
            for (int k = 0; k < 8; ++k) s[k] = ntld(&col[j + k]);
#pragma unroll
            for (int k = 0; k < 8; ++k) v[k] = yA[(size_t)s[k] * 2 + r];
#pragma unroll
            for (int k = 0; k < 8; ++k) {
                acc[0] += bflo(v[k].x); acc[1] += bfhi(v[k].x);
                acc[2] += bflo(v[k].y); acc[3] += bfhi(v[k].y);
                acc[4] += bflo(v[k].z); acc[5] += bfhi(v[k].z);
                acc[6] += bflo(v[k].w); acc[7] += bfhi(v[k].w);
            }
        }
        for (; j < b; ++j) {
            uint4 v = yA[(size_t)ntld(&col[j]) * 2 + r];
            acc[0] += bflo(v.x); acc[1] += bfhi(v.x);
            acc[2] += bflo(v.y); acc[3] += bfhi(v.y);
            acc[4] += bflo(v.z); acc[5] += bfhi(v.z);
            acc[6] += bflo(v.w); acc[7] += bfhi(v.w);
        }
        // merge the two edge-halves (lanes l and l^1 share node i and r)
#pragma unroll
        for (int k = 0; k < 8; ++k) acc[k] += __shfl_xor(acc[k], 1);
        if (!half) {
            float* lp = &lpool[g * 16 + r * 8];
#pragma unroll
            for (int k = 0; k < 8; ++k) atomicAdd(&lp[k], acc[k] * di);
        }
    }
    __syncthreads();
    float* pp = partA + (size_t)blockIdx.x * (NGRAPHS * 16);
    for (int k = threadIdx.x; k < NGRAPHS * 16; k += 256) pp[k] = lpool[k];
}

__global__ void gather3B(const int2* __restrict__ rowBE, const int* __restrict__ col,
                         const uint4* __restrict__ yB, const int2* __restrict__ dg,
                         float* __restrict__ partB, float* __restrict__ cpart) {
    __shared__ float lpool[NGRAPHS * 8];
    __shared__ float lcnt[NGRAPHS];
    for (int k = threadIdx.x; k < NGRAPHS * 8; k += 256) lpool[k] = 0.0f;
    for (int k = threadIdx.x; k < NGRAPHS; k += 256) lcnt[k] = 0.0f;
    __syncthreads();

    const int T = NNODES * 2;
    const int stride = NBLKB * 256;
    for (int t = blockIdx.x * 256 + threadIdx.x; t < T; t += stride) {
        int i = t >> 1;
        int half = t & 1;
        int2 wi = ntld2(&dg[i]);
        float di = __int_as_float(wi.x);
        int g = wi.y;
        int2 be = ntld2(&rowBE[i]);
        int mid = be.x + ((be.y - be.x + 1) >> 1);
        int a = half ? mid : be.x;
        int b = half ? be.y : mid;
        float acc[8] = {0, 0, 0, 0, 0, 0, 0, 0};
        if (!half) {
            uint4 sv = yB[i];
            acc[0] = bflo(sv.x); acc[1] = bfhi(sv.x);
            acc[2] = bflo(sv.y); acc[3] = bfhi(sv.y);
            acc[4] = bflo(sv.z); acc[5] = bfhi(sv.z);
            acc[6] = bflo(sv.w); acc[7] = bfhi(sv.w);
        }
        int j = a;
        for (; j + 8 <= b; j += 8) {
            int s[8];
            uint4 v[8];
#pragma unroll
            for (int k = 0; k < 8; ++k) s[k] = ntld(&col[j + k]);
#pragma unroll
            for (int k = 0; k < 8; ++k) v[k] = yB[s[k]];
#pragma unroll
            for (int k = 0; k < 8; ++k) {
                acc[0] += bflo(v[k].x); acc[1] += bfhi(v[k].x);
                acc[2] += bflo(v[k].y); acc[3] += bfhi(v[k].y);
                acc[4] += bflo(v[k].z); acc[5] += bfhi(v[k].z);
                acc[6] += bflo(v[k].w); acc[7] += bfhi(v[k].w);
            }
        }
        for (; j < b; ++j) {
            uint4 v = yB[ntld(&col[j])];
            acc[0] += bflo(v.x); acc[1] += bfhi(v.x);
            acc[2] += bflo(v.y); acc[3] += bfhi(v.y);
            acc[4] += bflo(v.z); acc[5] += bfhi(v.z);
            acc[6] += bflo(v.w); acc[7] += bfhi(v.w);
        }
#pragma unroll
        for (int k = 0; k < 8; ++k) acc[k] += __shfl_xor(acc[k], 1);
        if (!half) {
            float* lp = &lpool[g * 8];
#pragma unroll
            for (int k = 0; k < 8; ++k) atomicAdd(&lp[k], acc[k] * di);
            atomicAdd(&lcnt[g], 1.0f);
        }
    }
    __syncthreads();
    float* pp = partB + (size_t)blockIdx.x * (NGRAPHS * 8);
    for (int k = threadIdx.x; k < NGRAPHS * 8; k += 256) pp[k] = lpool[k];
    float* cp = cpart + (size_t)blockIdx.x * NGRAPHS;
    for (int k = threadIdx.x; k < NGRAPHS; k += 256) cp[k] = lcnt[k];
}

// one wave (64 lanes) per output element; lanes stride over the block partials
__global__ void pool_finish(const float* __restrict__ partA, const float* __restrict__ partB,
                            const float* __restrict__ cpart, const float* __restrict__ b3,
                            float* __restrict__ out) {
    int w = blockIdx.x * 4 + (threadIdx.x >> 6);
    int lane = threadIdx.x & 63;
    if (w >= NGRAPHS * 24) return;
    int g = w / 24;
    int c = w - g * 24;
    float s = 0.0f, cn = 0.0f;
    if (c < 16) {
        for (int b = lane; b < NBLKA; b += 64) s += partA[(size_t)b * (NGRAPHS * 16) + g * 16 + c];
    } else {
        for (int b = lane; b < NBLKB; b += 64) s += partB[(size_t)b * (NGRAPHS * 8) + g * 8 + (c - 16)];
    }
    for (int b = lane; b < NBLKB; b += 64) cn += cpart[(size_t)b * NGRAPHS + g];
#pragma unroll
    for (int off = 32; off > 0; off >>= 1) {
        s += __shfl_down(s, off);
        cn += __shfl_down(cn, off);
    }
    if (lane == 0) out[w] = tanhf(s / fmaxf(cn, 1.0f) + b3[c]);
}

// ---------------- launch ----------------

static inline int gridFor(long long total, int block) {
    return (int)((total + block - 1) / block);
}

extern "C" void kernel_launch(void* const* d_in, const int* in_sizes, int n_in,
                              void* d_out, int out_size, void* d_ws, size_t ws_size,
                              hipStream_t stream) {
    const float* pos   = (const float*)d_in[0];
    const int*   ei    = (const int*)d_in[1];
    const int*   batch = (const int*)d_in[2];
    const float* W1    = (const float*)d_in[3];
    const float* b1    = (const float*)d_in[4];
    const float* W2    = (const float*)d_in[5];
    const float* b2    = (const float*)d_in[6];
    const float* W3    = (const float*)d_in[7];
    const float* b3    = (const float*)d_in[8];
    float*       out   = (float*)d_out;

    const int N = NNODES;
    const int E = in_sizes[1] / 2;
    const int* src = ei;
    const int* dst = ei + E;

    // ---- workspace layout (16B-aligned chunks first) ----
    char* p = (char*)d_ws;
    uint4*  z2b    = (uint4*)p;         p += (size_t)N * 8 * sizeof(uint4);   // bf16 z2' [N,64]
    uint4*  yA     = (uint4*)p;         p += (size_t)N * 2 * sizeof(uint4);   // bf16 y0' ch0-15 (3.2MB)
    uint4*  yB     = (uint4*)p;         p += (size_t)N * 1 * sizeof(uint4);   // bf16 y0' ch16-23 (1.6MB)
    float4* pos4   = (float4*)p;        p += (size_t)N * sizeof(float4);      // {pos*di, di}
    int2*   rowBE  = (int2*)p;          p += (size_t)N * sizeof(int2);
    int2*   dg     = (int2*)p;          p += (size_t)N * sizeof(int2);
    float*  dinv   = (float*)p;         p += (size_t)N * sizeof(float);
    int*    bCur   = (int*)p;           p += NB * sizeof(int);
    unsigned int* packed = (unsigned int*)p;  p += (size_t)NB * CAP * sizeof(unsigned int);
    int*    col    = (int*)p;           p += (size_t)NB * CAP * sizeof(int);
    // partials aliased onto z2b (12.8MB; dead after gather2_mm3):
    // partA 2048*64*16*4 = 8MB, partB 1024*64*8*4 = 2MB, cpart 1024*64*4 = 256KB -> 10.25MB OK.
    float*  partA  = (float*)z2b;
    float*  partB  = partA + (size_t)NBLKA * NGRAPHS * 16;
    float*  cpartB = partB + (size_t)NBLKB * NGRAPHS * 8;

    const int B = 256;
    const int edgeBlocks = gridFor(E, 2048);

    // ---- CSR build: 2 kernels, fixed-capacity buckets ----
    hipMemsetAsync(bCur, 0, NB * sizeof(int), stream);
    bucket_scatter<<<edgeBlocks, 256, 0, stream>>>(src, dst, bCur, packed, E);
    bucket_build<<<NB, 256, 0, stream>>>(packed, bCur, batch, pos, rowBE, col, dinv, dg, pos4, N);

    // ---- fused pos-gather + mm1 + mm2 -> z2' bf16 ----
    mm12_gp<<<gridFor(N, 64), 256, 0, stream>>>(pos4, rowBE, col, dinv, W1, b1, W2, (uint2*)z2b, N);

    // ---- fused layer-2 gather + layer-3 matmul -> yA/yB directly (h2 never materialized) ----
    gather2_mm3<<<gridFor((long long)N * 8, B), B, 0, stream>>>(rowBE, col, z2b, dinv, b2, W3,
                                                                (uint2*)yA, (uint2*)yB);

    // ---- channel-phased gather+pool ----
    gather3A<<<NBLKA, 256, 0, stream>>>(rowBE, col, yA, dg, partA);
    gather3B<<<NBLKB, 256, 0, stream>>>(rowBE, col, yB, dg, partB, cpartB);
    pool_finish<<<gridFor((long long)NGRAPHS * 24 * 64, B), B, 0, stream>>>(partA, partB, cpartB, b3, out);
}

// Round 8
// 256.328 us; speedup vs baseline: 1.1872x; 1.0587x over previous
//
#include <hip/hip_runtime.h>
#include <math.h>

#define NNODES 100000
#define NGRAPHS 64
#define NB 391       // ceil(100000 / 256) buckets of 256 nodes
#define CAP 4608     // fixed bucket capacity (mean 4096, +8 sigma margin)
#define NBLKA 1024   // gather3A grid (4 blocks/CU — r7 showed 8/CU regresses: partials traffic)
#define NBLKB 512    // gather3B grid

// ---------- bf16 helpers (RNE pack, shift unpack) ----------

__device__ __forceinline__ unsigned int f2bf(float x) {
    union { float f; unsigned int u; } v;
    v.f = x;
    unsigned int r = v.u + 0x7FFFu + ((v.u >> 16) & 1u);
    return r >> 16;
}
__device__ __forceinline__ unsigned int pack2bf(float lo, float hi) {
    return f2bf(lo) | (f2bf(hi) << 16);
}
__device__ __forceinline__ float bflo(unsigned int u) {
    union { unsigned int u; float f; } v;
    v.u = u << 16;
    return v.f;
}
__device__ __forceinline__ float bfhi(unsigned int u) {
    union { unsigned int u; float f; } v;
    v.u = u & 0xFFFF0000u;
    return v.f;
}

// ---------- non-temporal load helpers (keep streams out of per-XCD L2) ----------

__device__ __forceinline__ int ntld(const int* p) { return __builtin_nontemporal_load(p); }
__device__ __forceinline__ int2 ntld2(const int2* p) {
    long long v = __builtin_nontemporal_load((const long long*)p);
    int2 r;
    r.x = (int)(unsigned int)(v & 0xffffffffLL);
    r.y = (int)(v >> 32);
    return r;
}

// ================= bucketed CSR build (2 kernels, fixed-capacity buckets) =================
// bucket = dst >> 8; packed edge = (dst & 255) << 17 | src  (src < 2^17)

__global__ void bucket_scatter(const int* __restrict__ src, const int* __restrict__ dst,
                               int* __restrict__ bCur, unsigned int* __restrict__ packed,
                               int E) {
    __shared__ int h[NB];
    __shared__ int cur[NB];
    for (int k = threadIdx.x; k < NB; k += 256) h[k] = 0;
    __syncthreads();
    int base = blockIdx.x * 2048 + threadIdx.x;
    int d[8], s[8], b[8];
#pragma unroll
    for (int k = 0; k < 8; ++k) {
        int e = base + k * 256;
        if (e < E) {
            d[k] = dst[e];
            s[k] = src[e];
            b[k] = d[k] >> 8;
            atomicAdd(&h[b[k]], 1);
        }
    }
    __syncthreads();
    for (int k = threadIdx.x; k < NB; k += 256) {
        int c = h[k];
        cur[k] = c ? atomicAdd(&bCur[k], c) : 0;
    }
    __syncthreads();
#pragma unroll
    for (int k = 0; k < 8; ++k) {
        int e = base + k * 256;
        if (e < E) {
            int pos = atomicAdd(&cur[b[k]], 1);
            if (pos < CAP)
                packed[(size_t)b[k] * CAP + pos] = ((unsigned int)(d[k] & 255) << 17) | (unsigned int)s[k];
        }
    }
}

// one block per bucket: histogram -> rowBE + dinv + dg + pos4 (= pos*dinv, dinv) + sorted col
__global__ void bucket_build(const unsigned int* __restrict__ packed, const int* __restrict__ bCur,
                             const int* __restrict__ batch, const float* __restrict__ pos,
                             int2* __restrict__ rowBE, int* __restrict__ col,
                             float* __restrict__ dinv, int2* __restrict__ dg,
                             float4* __restrict__ pos4, int N_) {
    __shared__ int cnt[256];
    __shared__ int bas[256];
    int tid = threadIdx.x;
    int b = blockIdx.x;
    int count = bCur[b];
    if (count > CAP) count = CAP;
    int beg = b * CAP;
    cnt[tid] = 0;
    __syncthreads();
    for (int k = beg + tid; k < beg + count; k += 256) atomicAdd(&cnt[packed[k] >> 17], 1);
    __syncthreads();
    int myCnt = cnt[tid];
    bas[tid] = myCnt;
    __syncthreads();
    for (int off = 1; off < 256; off <<= 1) {
        int v = (tid >= off) ? bas[tid - off] : 0;
        __syncthreads();
        bas[tid] += v;
        __syncthreads();
    }
    int excl = beg + ((tid > 0) ? bas[tid - 1] : 0);
    int node = (b << 8) + tid;
    if (node < N_) {
        rowBE[node] = make_int2(excl, excl + myCnt);
        float di = rsqrtf((float)myCnt + 1.0f);
        dinv[node] = di;
        dg[node] = make_int2(__float_as_int(di), batch[node]);
        pos4[node] = make_float4(pos[node * 3] * di, pos[node * 3 + 1] * di,
                                 pos[node * 3 + 2] * di, di);
    }
    __syncthreads();
    bas[tid] = excl;
    __syncthreads();
    for (int k = beg + tid; k < beg + count; k += 256) {
        unsigned int p = packed[k];
        int pos_ = atomicAdd(&bas[p >> 17], 1);
        col[pos_] = (int)(p & 0x1FFFFu);
    }
}

// ---------------- fused pos-gather + layer1-mm + layer2-mm -> bf16 z2' (= z2*dinv) ------------

__global__ void mm12_gp(const float4* __restrict__ pos4, const int2* __restrict__ rowBE,
                        const int* __restrict__ col, const float* __restrict__ dinv,
                        const float* __restrict__ W1, const float* __restrict__ b1,
                        const float* __restrict__ W2, uint2* __restrict__ outb, int n) {
    __shared__ float4 part[256];
    __shared__ float4 ag[64];   // .xyz = pre-di aggregate, .w = di
    __shared__ float xs[64][65];
    __shared__ float4 ws[64 * 16];
    const int tid = threadIdx.x;
    const int rowBase = blockIdx.x * 64;
    const int r = tid >> 2, t4 = tid & 3;
    const int i = rowBase + r;

    float sx = 0, sy = 0, sz = 0, dival = 0;
    if (i < n) {
        int2 be = rowBE[i];
        float4 ps = pos4[i];
        dival = ps.w;
        if (t4 == 0) { sx = ps.x; sy = ps.y; sz = ps.z; }  // self: pos*di already
        for (int j = be.x + t4; j < be.y; j += 4) {
            float4 v = pos4[ntld(&col[j])];
            sx += v.x; sy += v.y; sz += v.z;
        }
    }
    part[tid] = make_float4(sx, sy, sz, dival);
    const float4* W24 = (const float4*)W2;
    for (int idx = tid; idx < 64 * 16; idx += 256) ws[idx] = W24[idx];
    __syncthreads();
    if (tid < 64) {
        float4 p0 = part[tid * 4], p1 = part[tid * 4 + 1];
        float4 p2 = part[tid * 4 + 2], p3 = part[tid * 4 + 3];
        ag[tid] = make_float4((p0.x + p1.x) + (p2.x + p3.x),
                              (p0.y + p1.y) + (p2.y + p3.y),
                              (p0.z + p1.z) + (p2.z + p3.z), p0.w);
    }
    __syncthreads();
    for (int idx = tid; idx < 64 * 64; idx += 256) {
        int rr = idx >> 6;
        int k = idx & 63;
        float4 a = ag[rr];
        float v = b1[k] + a.w * (a.x * W1[k] + a.y * W1[64 + k] + a.z * W1[128 + k]);
        xs[rr][k] = fmaxf(v, 0.0f);
    }
    __syncthreads();

    const int f4 = tid & 15;
    const int r0 = (tid >> 4) * 4;
    float4 a0 = make_float4(0, 0, 0, 0), a1 = a0, a2 = a0, a3 = a0;
#pragma unroll 4
    for (int k = 0; k < 64; ++k) {
        float4 wv = ws[k * 16 + f4];
        float xa = xs[r0 + 0][k];
        float xb = xs[r0 + 1][k];
        float xc = xs[r0 + 2][k];
        float xd = xs[r0 + 3][k];
        a0.x += wv.x * xa; a0.y += wv.y * xa; a0.z += wv.z * xa; a0.w += wv.w * xa;
        a1.x += wv.x * xb; a1.y += wv.y * xb; a1.z += wv.z * xb; a1.w += wv.w * xb;
        a2.x += wv.x * xc; a2.y += wv.y * xc; a2.z += wv.z * xc; a2.w += wv.w * xc;
        a3.x += wv.x * xd; a3.y += wv.y * xd; a3.z += wv.z * xd; a3.w += wv.w * xd;
    }
    int i0 = rowBase + r0;
    float d0 = (i0 + 0 < n) ? dinv[i0 + 0] : 1.0f;
    float d1 = (i0 + 1 < n) ? dinv[i0 + 1] : 1.0f;
    float d2 = (i0 + 2 < n) ? dinv[i0 + 2] : 1.0f;
    float d3 = (i0 + 3 < n) ? dinv[i0 + 3] : 1.0f;
    if (i0 + 0 < n)
        outb[(size_t)(i0 + 0) * 16 + f4] = make_uint2(pack2bf(a0.x * d0, a0.y * d0), pack2bf(a0.z * d0, a0.w * d0));
    if (i0 + 1 < n)
        outb[(size_t)(i0 + 1) * 16 + f4] = make_uint2(pack2bf(a1.x * d1, a1.y * d1), pack2bf(a1.z * d1, a1.w * d1));
    if (i0 + 2 < n)
        outb[(size_t)(i0 + 2) * 16 + f4] = make_uint2(pack2bf(a2.x * d2, a2.y * d2), pack2bf(a2.z * d2, a2.w * d2));
    if (i0 + 3 < n)
        outb[(size_t)(i0 + 3) * 16 + f4] = make_uint2(pack2bf(a3.x * d3, a3.y * d3), pack2bf(a3.z * d3, a3.w * d3));
}

// ---------------- fused gather layer2 + layer-3 matmul -> bf16 yA/yB directly ----------------
// Per block: 256 threads = 32 nodes x 8 channel-lanes. Phase 1: each lane accumulates 8
// channels over the node's edges, h2 = relu(acc*di + b2) -> stage f32 in LDS. Phase 2:
// 192 tasks (32 nodes x 6 col-quads) compute y0' = (h2 @ W3)*di -> split tables.

__device__ __forceinline__ void st_y(uint2* __restrict__ yA, uint2* __restrict__ yB,
                                     int i, int f4, uint2 v) {
    if (f4 < 4) yA[(size_t)i * 4 + f4] = v;
    else        yB[(size_t)i * 2 + (f4 - 4)] = v;
}

__global__ void gather2_mm3(const int2* __restrict__ rowBE, const int* __restrict__ col,
                            const uint4* __restrict__ h, const float* __restrict__ dinv,
                            const float* __restrict__ bias, const float* __restrict__ W3,
                            uint2* __restrict__ yA, uint2* __restrict__ yB) {
    __shared__ float hs[32][65];   // f32 h2 rows for this block's 32 nodes
    __shared__ float dd[32];       // dinv per local node
    __shared__ float w3s[64 * 24]; // W3 [k][c] row-major (6KB)
    const int tid = threadIdx.x;
    for (int idx = tid; idx < 64 * 24 / 4; idx += 256)
        ((float4*)w3s)[idx] = ((const float4*)W3)[idx];

    const int t = blockIdx.x * 256 + tid;   // grid is exact: N*8/256 = 3125 blocks
    const int i = t >> 3;
    const int c8 = t & 7;
    const float di = dinv[i];
    const int2 be = rowBE[i];
    float acc[8];
    {
        uint4 sv = h[t];  // z2'[i] = z2[i]*di  -> exactly the self-loop inner term
        acc[0] = bflo(sv.x); acc[1] = bfhi(sv.x);
        acc[2] = bflo(sv.y); acc[3] = bfhi(sv.y);
        acc[4] = bflo(sv.z); acc[5] = bfhi(sv.z);
        acc[6] = bflo(sv.w); acc[7] = bfhi(sv.w);
    }
    int j = be.x;
    for (; j + 8 <= be.y; j += 8) {
        int s[8];
        uint4 v[8];
#pragma unroll
        for (int k = 0; k < 8; ++k) s[k] = ntld(&col[j + k]);
#pragma unroll
        for (int k = 0; k < 8; ++k) v[k] = h[(size_t)s[k] * 8 + c8];
#pragma unroll
        for (int k = 0; k < 8; ++k) {
            acc[0] += bflo(v[k].x); acc[1] += bfhi(v[k].x);
            acc[2] += bflo(v[k].y); acc[3] += bfhi(v[k].y);
            acc[4] += bflo(v[k].z); acc[5] += bfhi(v[k].z);
            acc[6] += bflo(v[k].w); acc[7] += bfhi(v[k].w);
        }
    }
    for (; j < be.y; ++j) {
        uint4 v = h[(size_t)ntld(&col[j]) * 8 + c8];
        acc[0] += bflo(v.x); acc[1] += bfhi(v.x);
        acc[2] += bflo(v.y); acc[3] += bfhi(v.y);
        acc[4] += bflo(v.z); acc[5] += bfhi(v.z);
        acc[6] += bflo(v.w); acc[7] += bfhi(v.w);
    }
    const int il = tid >> 3;
    {
        const float* bv = bias + c8 * 8;
        float* hp = &hs[il][c8 * 8];
#pragma unroll
        for (int k = 0; k < 8; ++k) hp[k] = fmaxf(acc[k] * di + bv[k], 0.0f);
        if (c8 == 0) dd[il] = di;
    }
    __syncthreads();

    // Phase 2: 32 nodes x 6 col-quads; each task: 4 output cols, 64 MACs each
    if (tid < 192) {
        const int node = tid / 6;
        const int f4 = tid - node * 6;
        const int gi = blockIdx.x * 32 + node;
        const float dloc = dd[node];
        const float* hrow = hs[node];
        const float* wp = &w3s[f4 * 4];
        float c0 = 0, c1 = 0, c2 = 0, c3 = 0;
#pragma unroll 4
        for (int k = 0; k < 64; ++k) {
            float hv = hrow[k];
            c0 += hv * wp[k * 24 + 0];
            c1 += hv * wp[k * 24 + 1];
            c2 += hv * wp[k * 24 + 2];
            c3 += hv * wp[k * 24 + 3];
        }
        st_y(yA, yB, gi, f4, make_uint2(pack2bf(c0 * dloc, c1 * dloc),
                                        pack2bf(c2 * dloc, c3 * dloc)));
    }
}

// ---------------- gather layer3 + pool, channel-phased so the table fits per-XCD L2 ----------
// gather3A: ch0-15 from yA (3.2MB). 4 tasks/node: (half = bit0, r = bit1).
// gather3B: ch16-23 from yB (1.6MB) + node counts. 2 tasks/node (half = bit0).
// Edge halves merged in-wave via shfl_xor(1); col/rowBE/dg non-temporal.

__global__ void gather3A(const int2* __restrict__ rowBE, const int* __restrict__ col,
                         const uint4* __restrict__ yA, const int2* __restrict__ dg,
                         float* __restrict__ partA) {
    __shared__ float lpool[NGRAPHS * 16];
    for (int k = threadIdx.x; k < NGRAPHS * 16; k += 256) lpool[k] = 0.0f;
    __syncthreads();

    const int T = NNODES * 4;
    const int stride = NBLKA * 256;
    for (int t = blockIdx.x * 256 + threadIdx.x; t < T; t += stride) {
        int i = t >> 2;
        int half = t & 1;
        int r = (t >> 1) & 1;
        int2 wi = ntld2(&dg[i]);
        float di = __int_as_float(wi.x);
        int g = wi.y;
        int2 be = ntld2(&rowBE[i]);
        int mid = be.x + ((be.y - be.x + 1) >> 1);
        int a = half ? mid : be.x;
        int b = half ? be.y : mid;
        float acc[8] = {0, 0, 0, 0, 0, 0, 0, 0};
        if (!half) {
            uint4 sv = yA[(size_t)i * 2 + r];  // self term (pre-scaled)
            acc[0] = bflo(sv.x); acc[1] = bfhi(sv.x);
            acc[2] = bflo(sv.y); acc[3] = bfhi(sv.y);
            acc[4] = bflo(sv.z); acc[5] = bfhi(sv.z);
            acc[6] = bflo(sv.w); acc[7] = bfhi(sv.w);
        }
        int j = a;
        for (; j + 8 <= b; j += 8) {
            int s[8];
            uint4 v[8];
#pragma unroll
            for (int k = 0; k < 8; ++k) s[k] = ntld(&col[j + k]);
#pragma unroll
            for (int k = 0; k < 8; ++k) v[k] = yA[(size_t)s[k] * 2 + r];
#pragma unroll
            for (int k = 0; k < 8; ++k) {
                acc[0] += bflo(v[k].x); acc[1] += bfhi(v[k].x);
                acc[2] += bflo(v[k].y); acc[3] += bfhi(v[k].y);
                acc[4] += bflo(v[k].z); acc[5] += bfhi(v[k].z);
                acc[6] += bflo(v[k].w); acc[7] += bfhi(v[k].w);
            }
        }
        for (; j < b; ++j) {
            uint4 v = yA[(size_t)ntld(&col[j]) * 2 + r];
            acc[0] += bflo(v.x); acc[1] += bfhi(v.x);
            acc[2] += bflo(v.y); acc[3] += bfhi(v.y);
            acc[4] += bflo(v.z); acc[5] += bfhi(v.z);
            acc[6] += bflo(v.w); acc[7] += bfhi(v.w);
        }
        // merge the two edge-halves (lanes l and l^1 share node i and r)
#pragma unroll
        for (int k = 0; k < 8; ++k) acc[k] += __shfl_xor(acc[k], 1);
        if (!half) {
            float* lp = &lpool[g * 16 + r * 8];
#pragma unroll
            for (int k = 0; k < 8; ++k) atomicAdd(&lp[k], acc[k] * di);
        }
    }
    __syncthreads();
    float* pp = partA + (size_t)blockIdx.x * (NGRAPHS * 16);
    for (int k = threadIdx.x; k < NGRAPHS * 16; k += 256) pp[k] = lpool[k];
}

__global__ void gather3B(const int2* __restrict__ rowBE, const int* __restrict__ col,
                         const uint4* __restrict__ yB, const int2* __restrict__ dg,
                         float* __restrict__ partB, float* __restrict__ cpart) {
    __shared__ float lpool[NGRAPHS * 8];
    __shared__ float lcnt[NGRAPHS];
    for (int k = threadIdx.x; k < NGRAPHS * 8; k += 256) lpool[k] = 0.0f;
    for (int k = threadIdx.x; k < NGRAPHS; k += 256) lcnt[k] = 0.0f;
    __syncthreads();

    const int T = NNODES * 2;
    const int stride = NBLKB * 256;
    for (int t = blockIdx.x * 256 + threadIdx.x; t < T; t += stride) {
        int i = t >> 1;
        int half = t & 1;
        int2 wi = ntld2(&dg[i]);
        float di = __int_as_float(wi.x);
        int g = wi.y;
        int2 be = ntld2(&rowBE[i]);
        int mid = be.x + ((be.y - be.x + 1) >> 1);
        int a = half ? mid : be.x;
        int b = half ? be.y : mid;
        float acc[8] = {0, 0, 0, 0, 0, 0, 0, 0};
        if (!half) {
            uint4 sv = yB[i];
            acc[0] = bflo(sv.x); acc[1] = bfhi(sv.x);
            acc[2] = bflo(sv.y); acc[3] = bfhi(sv.y);
            acc[4] = bflo(sv.z); acc[5] = bfhi(sv.z);
            acc[6] = bflo(sv.w); acc[7] = bfhi(sv.w);
        }
        int j = a;
        for (; j + 8 <= b; j += 8) {
            int s[8];
            uint4 v[8];
#pragma unroll
            for (int k = 0; k < 8; ++k) s[k] = ntld(&col[j + k]);
#pragma unroll
            for (int k = 0; k < 8; ++k) v[k] = yB[s[k]];
#pragma unroll
            for (int k = 0; k < 8; ++k) {
                acc[0] += bflo(v[k].x); acc[1] += bfhi(v[k].x);
                acc[2] += bflo(v[k].y); acc[3] += bfhi(v[k].y);
                acc[4] += bflo(v[k].z); acc[5] += bfhi(v[k].z);
                acc[6] += bflo(v[k].w); acc[7] += bfhi(v[k].w);
            }
        }
        for (; j < b; ++j) {
            uint4 v = yB[ntld(&col[j])];
            acc[0] += bflo(v.x); acc[1] += bfhi(v.x);
            acc[2] += bflo(v.y); acc[3] += bfhi(v.y);
            acc[4] += bflo(v.z); acc[5] += bfhi(v.z);
            acc[6] += bflo(v.w); acc[7] += bfhi(v.w);
        }
#pragma unroll
        for (int k = 0; k < 8; ++k) acc[k] += __shfl_xor(acc[k], 1);
        if (!half) {
            float* lp = &lpool[g * 8];
#pragma unroll
            for (int k = 0; k < 8; ++k) atomicAdd(&lp[k], acc[k] * di);
            atomicAdd(&lcnt[g], 1.0f);
        }
    }
    __syncthreads();
    float* pp = partB + (size_t)blockIdx.x * (NGRAPHS * 8);
    for (int k = threadIdx.x; k < NGRAPHS * 8; k += 256) pp[k] = lpool[k];
    float* cp = cpart + (size_t)blockIdx.x * NGRAPHS;
    for (int k = threadIdx.x; k < NGRAPHS; k += 256) cp[k] = lcnt[k];
}

// one wave (64 lanes) per output element; lanes stride over the block partials
__global__ void pool_finish(const float* __restrict__ partA, const float* __restrict__ partB,
                            const float* __restrict__ cpart, const float* __restrict__ b3,
                            float* __restrict__ out) {
    int w = blockIdx.x * 4 + (threadIdx.x >> 6);
    int lane = threadIdx.x & 63;
    if (w >= NGRAPHS * 24) return;
    int g = w / 24;
    int c = w - g * 24;
    float s = 0.0f, cn = 0.0f;
    if (c < 16) {
        for (int b = lane; b < NBLKA; b += 64) s += partA[(size_t)b * (NGRAPHS * 16) + g * 16 + c];
    } else {
        for (int b = lane; b < NBLKB; b += 64) s += partB[(size_t)b * (NGRAPHS * 8) + g * 8 + (c - 16)];
    }
    for (int b = lane; b < NBLKB; b += 64) cn += cpart[(size_t)b * NGRAPHS + g];
#pragma unroll
    for (int off = 32; off > 0; off >>= 1) {
        s += __shfl_down(s, off);
        cn += __shfl_down(cn, off);
    }
    if (lane == 0) out[w] = tanhf(s / fmaxf(cn, 1.0f) + b3[c]);
}

// ---------------- launch ----------------

static inline int gridFor(long long total, int block) {
    return (int)((total + block - 1) / block);
}

extern "C" void kernel_launch(void* const* d_in, const int* in_sizes, int n_in,
                              void* d_out, int out_size, void* d_ws, size_t ws_size,
                              hipStream_t stream) {
    const float* pos   = (const float*)d_in[0];
    const int*   ei    = (const int*)d_in[1];
    const int*   batch = (const int*)d_in[2];
    const float* W1    = (const float*)d_in[3];
    const float* b1    = (const float*)d_in[4];
    const float* W2    = (const float*)d_in[5];
    const float* b2    = (const float*)d_in[6];
    const float* W3    = (const float*)d_in[7];
    const float* b3    = (const float*)d_in[8];
    float*       out   = (float*)d_out;

    const int N = NNODES;
    const int E = in_sizes[1] / 2;
    const int* src = ei;
    const int* dst = ei + E;

    // ---- workspace layout (16B-aligned chunks first) ----
    char* p = (char*)d_ws;
    uint4*  z2b    = (uint4*)p;         p += (size_t)N * 8 * sizeof(uint4);   // bf16 z2' [N,64]
    uint4*  yA     = (uint4*)p;         p += (size_t)N * 2 * sizeof(uint4);   // bf16 y0' ch0-15 (3.2MB)
    uint4*  yB     = (uint4*)p;         p += (size_t)N * 1 * sizeof(uint4);   // bf16 y0' ch16-23 (1.6MB)
    float4* pos4   = (float4*)p;        p += (size_t)N * sizeof(float4);      // {pos*di, di}
    int2*   rowBE  = (int2*)p;          p += (size_t)N * sizeof(int2);
    int2*   dg     = (int2*)p;          p += (size_t)N * sizeof(int2);
    float*  dinv   = (float*)p;         p += (size_t)N * sizeof(float);
    int*    bCur   = (int*)p;           p += NB * sizeof(int);
    unsigned int* packed = (unsigned int*)p;  p += (size_t)NB * CAP * sizeof(unsigned int);
    int*    col    = (int*)p;           p += (size_t)NB * CAP * sizeof(int);
    // partials aliased onto z2b (12.8MB; dead after gather2_mm3). partA 4MB + partB 1MB + cpart.
    float*  partA  = (float*)z2b;
    float*  partB  = partA + (size_t)NBLKA * NGRAPHS * 16;
    float*  cpartB = partB + (size_t)NBLKB * NGRAPHS * 8;

    const int B = 256;
    const int edgeBlocks = gridFor(E, 2048);

    // ---- CSR build: 2 kernels, fixed-capacity buckets ----
    hipMemsetAsync(bCur, 0, NB * sizeof(int), stream);
    bucket_scatter<<<edgeBlocks, 256, 0, stream>>>(src, dst, bCur, packed, E);
    bucket_build<<<NB, 256, 0, stream>>>(packed, bCur, batch, pos, rowBE, col, dinv, dg, pos4, N);

    // ---- fused pos-gather + mm1 + mm2 -> z2' bf16 ----
    mm12_gp<<<gridFor(N, 64), 256, 0, stream>>>(pos4, rowBE, col, dinv, W1, b1, W2, (uint2*)z2b, N);

    // ---- fused layer-2 gather + layer-3 matmul -> yA/yB directly (h2 never materialized) ----
    gather2_mm3<<<gridFor((long long)N * 8, B), B, 0, stream>>>(rowBE, col, z2b, dinv, b2, W3,
                                                                (uint2*)yA, (uint2*)yB);

    // ---- channel-phased gather+pool ----
    gather3A<<<NBLKA, 256, 0, stream>>>(rowBE, col, yA, dg, partA);
    gather3B<<<NBLKB, 256, 0, stream>>>(rowBE, col, yB, dg, partB, cpartB);
    pool_finish<<<gridFor((long long)NGRAPHS * 24 * 64, B), B, 0, stream>>>(partA, partB, cpartB, b3, out);
}